// Round 6
// baseline (1715.039 us; speedup 1.0000x reference)
//
#include <hip/hip_runtime.h>
#include <stdint.h>

constexpr int B = 512, S = 1024, IN = 32, H = 128;
constexpr int KTOT = IN + H;    // 160
constexpr int NJ = 4;           // k-slices (wave-uniform)
constexpr int KSL = KTOT / NJ;  // 40 k per slice
constexpr int KP = KSL / 2;     // 20 half2 pairs

typedef uint32_t u32;

// D = a.h0*b.h0 + a.h1*b.h1 + D  (fp16 inputs, fp32 accumulate)
__device__ __forceinline__ void dot2(float& c, u32 a, u32 b) {
  asm("v_dot2_f32_f16 %0, %1, %2, %0" : "+v"(c) : "v"(a), "v"(b));
}
__device__ __forceinline__ float sigm(float v) {
  float e = __builtin_amdgcn_exp2f(-1.4426950408889634f * v);
  return __builtin_amdgcn_rcpf(1.0f + e);
}
__device__ __forceinline__ float tanh_(float v) {
  float e = __builtin_amdgcn_exp2f(-2.8853900817779268f * v);
  return 2.0f * __builtin_amdgcn_rcpf(1.0f + e) - 1.0f;
}

// __launch_bounds__(512, 2): the ONLY occupancy declaration that empirically
// keeps the 80-reg weight array resident (r3: VGPR=112, no spill). Any "min 4
// waves/EU" form makes the allocator clamp to 64 VGPR and spill 45 regs/thread
// (r4/r5: WRITE_SIZE 42-47 MB). HW occupancy follows the ACTUAL VGPR count:
// ~112 <= 128 gives 4 waves/EU = 2 blocks/CU at runtime anyway.
__global__ __launch_bounds__(512, 2)
void lstm_fused(const float* __restrict__ x, const float* __restrict__ Wih,
                const float* __restrict__ Whh, const float* __restrict__ bih,
                const float* __restrict__ bhh, const float* __restrict__ Wlin,
                const float* __restrict__ blin, float* __restrict__ out) {
  __shared__ alignas(16) _Float16 hx[2][KTOT];  // ping-pong [x(32)|h(128)], fp16
  __shared__ alignas(16) float red[NJ][H][4];   // per-slice partials [j][g][gate]
  __shared__ float redf[H];

  const int tid = threadIdx.x;
  const int lane = tid & 63;
  const int w = tid >> 6;             // wave 0..7
  const int j = w >> 1;               // k-slice, wave-uniform
  const int g = (w & 1) * 64 + lane;  // gate-row this thread dots for
  const int b = blockIdx.x;           // one batch row per block
  const int par = b & 1;
  const int aw0 = par, aw1 = 6 + par; // act waves (stagger SIMDs by block parity)
  const bool isact = (w == aw0) || (w == aw1);
  const int ga = (w == aw0) ? lane : 64 + lane;  // act-wave's gate-row
  const int xw = 2 + par;             // x-prefetch wave

  // ---- weights -> packed half2 regs: 4 gates x 20 pairs = 80 VGPRs ----
  u32 wreg[4][KP];
#pragma unroll
  for (int c = 0; c < 4; ++c) {
    const int n = c * H + g;
#pragma unroll
    for (int pq = 0; pq < KP; ++pq) {
      const int k0 = KSL * j + 2 * pq, k1 = k0 + 1;
      const float f0 = (k0 < IN) ? Wih[n * IN + k0] : Whh[n * H + (k0 - IN)];
      const float f1 = (k1 < IN) ? Wih[n * IN + k1] : Whh[n * H + (k1 - IN)];
      union { _Float16 h[2]; u32 u; } cv;
      cv.h[0] = (_Float16)f0;
      cv.h[1] = (_Float16)f1;
      wreg[c][pq] = cv.u;
    }
  }
#pragma unroll
  for (int c = 0; c < 4; ++c)
#pragma unroll
    for (int pq = 0; pq < KP; ++pq) asm volatile("" : "+v"(wreg[c][pq]));

  float bias_a[4] = {0.f, 0.f, 0.f, 0.f};
  if (isact) {
#pragma unroll
    for (int c = 0; c < 4; ++c) bias_a[c] = bih[c * H + ga] + bhh[c * H + ga];
  }

  // ---- init: hx[0] = (x_0 | zeros); hx[1] zeroed ----
  const size_t xbase = (size_t)b * S * IN;
  if (tid < KTOT) {
    hx[0][tid] = (tid < IN) ? (_Float16)x[xbase + tid] : (_Float16)0.0f;
    hx[1][tid] = (_Float16)0.0f;
  }
  __syncthreads();

  float cc = 0.f, oa = 0.f;
  // slice base pointers hoisted out of the loop
  const uint4* const base0 = (const uint4*)((const char*)&hx[0][0] + j * (KSL * 2));
  const uint4* const base1 = (const uint4*)((const char*)&hx[1][0] + j * (KSL * 2));

  for (int s = 0; s < S; ++s) {
    const int np = (s & 1) ^ 1;
    const uint4* const pp = (s & 1) ? base1 : base0;
    float wl = 0.f;
    if (isact) wl = Wlin[s * H + ga];  // early issue; L2-resident

    // ---- dots: wave-broadcast LDS reads, consume each uint4 immediately ----
    float a0 = 0.f, a1 = 0.f, a2 = 0.f, a3 = 0.f;
#pragma unroll
    for (int q = 0; q < 5; ++q) {
      const uint4 v = pp[q];
      dot2(a0, v.x, wreg[0][4 * q + 0]);
      dot2(a1, v.x, wreg[1][4 * q + 0]);
      dot2(a2, v.x, wreg[2][4 * q + 0]);
      dot2(a3, v.x, wreg[3][4 * q + 0]);
      dot2(a0, v.y, wreg[0][4 * q + 1]);
      dot2(a1, v.y, wreg[1][4 * q + 1]);
      dot2(a2, v.y, wreg[2][4 * q + 1]);
      dot2(a3, v.y, wreg[3][4 * q + 1]);
      dot2(a0, v.z, wreg[0][4 * q + 2]);
      dot2(a1, v.z, wreg[1][4 * q + 2]);
      dot2(a2, v.z, wreg[2][4 * q + 2]);
      dot2(a3, v.z, wreg[3][4 * q + 2]);
      dot2(a0, v.w, wreg[0][4 * q + 3]);
      dot2(a1, v.w, wreg[1][4 * q + 3]);
      dot2(a2, v.w, wreg[2][4 * q + 3]);
      dot2(a3, v.w, wreg[3][4 * q + 3]);
    }
    *(float4*)&red[j][g][0] = make_float4(a0, a1, a2, a3);
    __syncthreads();  // A: partials visible

    if (isact) {
      const float4 r0 = *(const float4*)&red[0][ga][0];
      const float4 r1 = *(const float4*)&red[1][ga][0];
      const float4 r2 = *(const float4*)&red[2][ga][0];
      const float4 r3 = *(const float4*)&red[3][ga][0];
      const float gi = sigm(r0.x + r1.x + r2.x + r3.x + bias_a[0]);
      const float gf = sigm(r0.y + r1.y + r2.y + r3.y + bias_a[1]);
      const float gg = tanh_(r0.z + r1.z + r2.z + r3.z + bias_a[2]);
      const float go = sigm(r0.w + r1.w + r2.w + r3.w + bias_a[3]);
      cc = gf * cc + gi * gg;
      const float h = go * tanh_(cc);
      hx[np][IN + ga] = (_Float16)h;  // h_s for step s+1
      oa += h * wl;                   // fused output linear
    } else if ((w == xw) && (lane < IN) && (s + 1 < S)) {
      hx[np][lane] = (_Float16)x[xbase + (s + 1) * IN + lane];  // x_{s+1}
    }
    __syncthreads();  // B: hx[np] complete
  }

  // ---- final reduce of fused linear ----
  if (isact) redf[ga] = oa;
  __syncthreads();
  if (tid == 0) {
    float sum = blin[0];
    for (int k = 0; k < H; ++k) sum += redf[k];
    out[b] = sum;
  }
}

extern "C" void kernel_launch(void* const* d_in, const int* in_sizes, int n_in,
                              void* d_out, int out_size, void* d_ws, size_t ws_size,
                              hipStream_t stream) {
  const float* x    = (const float*)d_in[0];
  const float* Wih  = (const float*)d_in[1];
  const float* Whh  = (const float*)d_in[2];
  const float* bih  = (const float*)d_in[3];
  const float* bhh  = (const float*)d_in[4];
  const float* Wlin = (const float*)d_in[5];
  const float* blin = (const float*)d_in[6];
  float* outp = (float*)d_out;
  hipLaunchKernelGGL(lstm_fused, dim3(B), dim3(512), 0, stream,
                     x, Wih, Whh, bih, bhh, Wlin, blin, outp);
}

// Round 7
// 1414.941 us; speedup vs baseline: 1.2121x; 1.2121x over previous
//
#include <hip/hip_runtime.h>
#include <stdint.h>

constexpr int B = 512, S = 1024, IN = 32, H = 128;
constexpr int KTOT = IN + H;    // 160
constexpr int NJ = 4;           // k-slices (wave-uniform)
constexpr int KSL = KTOT / NJ;  // 40 k per slice
constexpr int KP = KSL / 2;     // 20 half2 pairs

typedef uint32_t u32;

// D = a.h0*b.h0 + a.h1*b.h1 + D  (fp16 inputs, fp32 accumulate)
__device__ __forceinline__ void dot2(float& c, u32 a, u32 b) {
  asm("v_dot2_f32_f16 %0, %1, %2, %0" : "+v"(c) : "v"(a), "v"(b));
}
__device__ __forceinline__ float sigm(float v) {
  float e = __builtin_amdgcn_exp2f(-1.4426950408889634f * v);
  return __builtin_amdgcn_rcpf(1.0f + e);
}
__device__ __forceinline__ float tanh_(float v) {
  float e = __builtin_amdgcn_exp2f(-2.8853900817779268f * v);
  return 2.0f * __builtin_amdgcn_rcpf(1.0f + e) - 1.0f;
}

// 1024-thread block = 16 waves = 4 waves/SIMD resident from a SINGLE block
// (r6 lesson: 2nd 512-thread block never co-resides at VGPR>64; a 1024-block
// needs no co-residency). 2 gates/thread -> 40 weight VGPRs; schedulability
// caps VGPR at 128 automatically. No min-waves hint (r4/r5 squeeze trigger).
__global__ __launch_bounds__(1024, 1)
void lstm_fused(const float* __restrict__ x, const float* __restrict__ Wih,
                const float* __restrict__ Whh, const float* __restrict__ bih,
                const float* __restrict__ bhh, const float* __restrict__ Wlin,
                const float* __restrict__ blin, float* __restrict__ out) {
  __shared__ alignas(16) _Float16 hx0[2][KTOT];   // row0 ping-pong [x|h]
  __shared__ alignas(16) _Float16 hx1[2][KTOT];   // row1
  __shared__ float red0[NJ][4][H];                // row0 partials [j][gate][g]
  __shared__ float red1[NJ][4][H];                // row1
  __shared__ float redf[2][H];

  const int tid = threadIdx.x;
  const int lane = tid & 63;
  const int w = tid >> 6;          // wave 0..15
  const int j = w >> 2;            // k-slice 0..3 (wave-uniform)
  const int cp = (w >> 1) & 1;     // gate-pair: 0 -> {i,f}, 1 -> {g,o}
  const int g = (w & 1) * 64 + lane;  // gate-row 0..127
  const int r0 = blockIdx.x * 2;   // this block's two batch rows

  // act waves on 4 DIFFERENT SIMDs (w&3 = 0,1,2,3): acts hide under the
  // other 3 waves' dots on each SIMD.
  const bool isact0 = (w == 0) || (w == 5);    // row0 act (P1 phase)
  const bool isact1 = (w == 10) || (w == 15);  // row1 act (P0 phase)
  const bool isact = isact0 || isact1;
  const int ga = ((w == 5) || (w == 15)) ? 64 + lane : lane;

  // ---- weights -> packed half2 regs: 2 gates x 20 pairs = 40 VGPRs ----
  u32 wreg[2][KP];
#pragma unroll
  for (int c2 = 0; c2 < 2; ++c2) {
    const int n = (2 * cp + c2) * H + g;
#pragma unroll
    for (int pq = 0; pq < KP; ++pq) {
      const int k0 = KSL * j + 2 * pq, k1 = k0 + 1;
      const float f0 = (k0 < IN) ? Wih[n * IN + k0] : Whh[n * H + (k0 - IN)];
      const float f1 = (k1 < IN) ? Wih[n * IN + k1] : Whh[n * H + (k1 - IN)];
      union { _Float16 h[2]; u32 u; } cv;
      cv.h[0] = (_Float16)f0;
      cv.h[1] = (_Float16)f1;
      wreg[c2][pq] = cv.u;
    }
  }
#pragma unroll
  for (int c2 = 0; c2 < 2; ++c2)
#pragma unroll
    for (int pq = 0; pq < KP; ++pq) asm volatile("" : "+v"(wreg[c2][pq]));

  float bias[4] = {0.f, 0.f, 0.f, 0.f};
  if (isact) {
#pragma unroll
    for (int c = 0; c < 4; ++c) bias[c] = bih[c * H + ga] + bhh[c * H + ga];
  }

  // ---- init: hx*[0] = (x_0 | zeros); hx*[1] zeroed ----
  const size_t xb0 = (size_t)r0 * S * IN, xb1 = (size_t)(r0 + 1) * S * IN;
  if (tid < KTOT) {
    hx0[0][tid] = (tid < IN) ? (_Float16)x[xb0 + tid] : (_Float16)0.0f;
    hx0[1][tid] = (_Float16)0.0f;
  } else if (tid < 2 * KTOT) {
    const int t = tid - KTOT;
    hx1[0][t] = (t < IN) ? (_Float16)x[xb1 + t] : (_Float16)0.0f;
    hx1[1][t] = (_Float16)0.0f;
  }
  __syncthreads();

  float cc = 0.f, oa = 0.f;  // per-act-thread LSTM cell + fused-linear acc

#define DOTS(HXBUF, REDBUF)                                             \
  {                                                                     \
    const uint4* pp = (const uint4*)((HXBUF) + j * KSL);                \
    float a0 = 0.f, a1 = 0.f;                                           \
    _Pragma("unroll") for (int q = 0; q < 5; ++q) {                     \
      const uint4 v = pp[q];                                            \
      dot2(a0, v.x, wreg[0][4 * q + 0]);                                \
      dot2(a1, v.x, wreg[1][4 * q + 0]);                                \
      dot2(a0, v.y, wreg[0][4 * q + 1]);                                \
      dot2(a1, v.y, wreg[1][4 * q + 1]);                                \
      dot2(a0, v.z, wreg[0][4 * q + 2]);                                \
      dot2(a1, v.z, wreg[1][4 * q + 2]);                                \
      dot2(a0, v.w, wreg[0][4 * q + 3]);                                \
      dot2(a1, v.w, wreg[1][4 * q + 3]);                                \
    }                                                                   \
    (REDBUF)[j][2 * cp][g] = a0;                                        \
    (REDBUF)[j][2 * cp + 1][g] = a1;                                    \
  }

#define ACT(REDBUF, HWRITE, WL)                                         \
  {                                                                     \
    const float s0 = (REDBUF)[0][0][ga] + (REDBUF)[1][0][ga] +          \
                     (REDBUF)[2][0][ga] + (REDBUF)[3][0][ga] + bias[0]; \
    const float s1 = (REDBUF)[0][1][ga] + (REDBUF)[1][1][ga] +          \
                     (REDBUF)[2][1][ga] + (REDBUF)[3][1][ga] + bias[1]; \
    const float s2 = (REDBUF)[0][2][ga] + (REDBUF)[1][2][ga] +          \
                     (REDBUF)[2][2][ga] + (REDBUF)[3][2][ga] + bias[2]; \
    const float s3 = (REDBUF)[0][3][ga] + (REDBUF)[1][3][ga] +          \
                     (REDBUF)[2][3][ga] + (REDBUF)[3][3][ga] + bias[3]; \
    const float gi = sigm(s0), gf = sigm(s1);                           \
    const float gg = tanh_(s2), go = sigm(s3);                          \
    cc = gf * cc + gi * gg;                                             \
    const float h = go * tanh_(cc);                                     \
    if (HWRITE) ((_Float16*)(HWRITE))[IN + ga] = (_Float16)h;           \
    oa += h * (WL);                                                     \
  }

  for (int s = 0; s < S; ++s) {
    const int p = s & 1, np = p ^ 1;
    // early Wlin load: act0 uses step s (in P1); act1 uses step s-1 (in P0)
    float wl = 0.f;
    if (isact0) wl = Wlin[s * H + ga];
    else if (isact1 && s > 0) wl = Wlin[(s - 1) * H + ga];

    // ---- P0: dots(row0, s)  ||  act(row1, s-1) ----
    DOTS(hx0[p], red0);
    if (isact1 && s > 0) ACT(red1, hx1[p], wl);  // h_{s-1} -> buffer dots1(s) reads
    __syncthreads();  // A: red0 complete; hx1[p].h complete

    // ---- P1: dots(row1, s)  ||  act(row0, s)  ||  x prefetch ----
    DOTS(hx1[p], red1);
    if (isact0) ACT(red0, hx0[np], wl);          // h_s -> buffer for step s+1
    if ((w == 2) && (s + 1 < S)) {
      const int row = lane >> 5, k = lane & 31;
      const float xv = x[(row ? xb1 : xb0) + (size_t)(s + 1) * IN + k];
      (row ? hx1 : hx0)[np][k] = (_Float16)xv;
    }
    __syncthreads();  // B: red1, hx0[np], x(s+1) complete
  }

  // ---- epilogue: act(row1, S-1) (pipeline tail) ----
  if (isact1) {
    const float wlf = Wlin[(S - 1) * H + ga];
    ACT(red1, (void*)0, wlf);
  }
  if (isact) redf[isact1 ? 1 : 0][ga] = oa;
  __syncthreads();
  if (tid < 2) {
    float sum = blin[0];
    for (int k = 0; k < H; ++k) sum += redf[tid][k];
    out[r0 + tid] = sum;
  }
#undef DOTS
#undef ACT
}

extern "C" void kernel_launch(void* const* d_in, const int* in_sizes, int n_in,
                              void* d_out, int out_size, void* d_ws, size_t ws_size,
                              hipStream_t stream) {
  const float* x    = (const float*)d_in[0];
  const float* Wih  = (const float*)d_in[1];
  const float* Whh  = (const float*)d_in[2];
  const float* bih  = (const float*)d_in[3];
  const float* bhh  = (const float*)d_in[4];
  const float* Wlin = (const float*)d_in[5];
  const float* blin = (const float*)d_in[6];
  float* outp = (float*)d_out;
  hipLaunchKernelGGL(lstm_fused, dim3(B / 2), dim3(1024), 0, stream,
                     x, Wih, Whh, bih, bhh, Wlin, blin, outp);
}